// Round 4
// baseline (1699.585 us; speedup 1.0000x reference)
//
#include <hip/hip_runtime.h>
#include <hip/hip_bf16.h>

// FluxSingleTransformerBlock forward, MI355X.
// Pipeline: weightsT->bf16 (just-in-time, shared buffer) | e=silu(temb)@w_ada |
// ln+modulate->x_bf16 | QKV gemm | rms+rope->q,k bf16, v->vt bf16 |
// flash attn -> concat[:,0:3072] | MLP1 gemm(gelu)->concat[:,3072:] |
// W2 gemm fused mask/gate/residual -> out.
// ws usage ~252 MB (wT buffer reused per-GEMM; cat aliases dead qkv buffer).

#define DIM    3072
#define NHEADS 24
#define HD     128
#define MLPD   12288
#define NB     2
#define TEXTL  256
#define IMGL   1024
#define SEQL   1280
#define NTOK   (NB*SEQL)
#define CATK   (DIM+MLPD)
#define EPSV   1e-6f

typedef unsigned short u16;
typedef __bf16 bf16x8 __attribute__((ext_vector_type(8)));
typedef float f32x4 __attribute__((ext_vector_type(4)));

__device__ __forceinline__ u16 f2bf(float f){
  unsigned u = __builtin_bit_cast(unsigned, f);
  u += 0x7fffu + ((u >> 16) & 1u);
  return (u16)(u >> 16);
}
__device__ __forceinline__ float siluf(float x){ return x / (1.f + __expf(-x)); }
__device__ __forceinline__ float geluf(float x){
  float t = 0.7978845608028654f * (x + 0.044715f * x * x * x);
  float th = 1.f - 2.f / (__expf(2.f * t) + 1.f);
  return 0.5f * x * (1.f + th);
}
__device__ __forceinline__ void ld_lds16(const void* g, void* l){
  __builtin_amdgcn_global_load_lds((const __attribute__((address_space(1))) void*)g,
                                   (__attribute__((address_space(3))) void*)l, 16, 0, 0);
}

// ---------------- weight fp32 -> bf16 transpose: W[K][N] -> WT[N][K] --------
__global__ __launch_bounds__(256)
void k_transpose_cvt(const float* __restrict__ W, u16* __restrict__ WT, int K, int N){
  __shared__ float tile[64][65];
  const int n0 = blockIdx.x * 64, k0 = blockIdx.y * 64;
  const int tx = threadIdx.x & 63, ty = threadIdx.x >> 6;
  #pragma unroll
  for (int i = 0; i < 16; ++i){
    const int r = ty + i*4;
    tile[r][tx] = W[(size_t)(k0 + r)*N + n0 + tx];
  }
  __syncthreads();
  #pragma unroll
  for (int i = 0; i < 16; ++i){
    const int r = ty + i*4;
    WT[(size_t)(n0 + r)*K + k0 + tx] = f2bf(tile[tx][r]);
  }
}

// ---------------- bias concat for batched QKV gemm --------------------------
__global__ void k_cat3(const float* __restrict__ a, const float* __restrict__ b,
                       const float* __restrict__ c, float* __restrict__ o){
  const int i = blockIdx.x*256 + threadIdx.x;
  if (i < DIM) o[i] = a[i];
  else if (i < 2*DIM) o[i] = b[i - DIM];
  else o[i] = c[i - 2*DIM];
}

// ---------------- e = silu(temb) @ w_ada + b_ada  (both batches) ------------
__global__ __launch_bounds__(256)
void k_ada(const float* __restrict__ temb, const float* __restrict__ w_ada,
           const float* __restrict__ b_ada, float* __restrict__ e){
  __shared__ float st[2*DIM];
  __shared__ float red[4][2][64];
  const int t = threadIdx.x;
  for (int i = t; i < 2*DIM; i += 256) st[i] = siluf(temb[i]);
  __syncthreads();
  const int tx = t & 63, ty = t >> 6;
  const int col = blockIdx.x*64 + tx;
  float a0 = 0.f, a1 = 0.f;
  for (int k = ty*768; k < ty*768 + 768; ++k){
    const float w = w_ada[(size_t)k*9216 + col];
    a0 += st[k]*w; a1 += st[DIM + k]*w;
  }
  red[ty][0][tx] = a0; red[ty][1][tx] = a1;
  __syncthreads();
  if (ty == 0){
    float s0 = red[0][0][tx] + red[1][0][tx] + red[2][0][tx] + red[3][0][tx];
    float s1 = red[0][1][tx] + red[1][1][tx] + red[2][1][tx] + red[3][1][tx];
    e[col]        = s0 + b_ada[col];
    e[9216 + col] = s1 + b_ada[col];
  }
}

// ---------------- tm[b,c] = mean over text tokens of hidden ----------------
__global__ void k_tmean(const float* __restrict__ h, float* __restrict__ tm){
  const int b = blockIdx.y;
  const int c = blockIdx.x*256 + threadIdx.x;
  float s = 0.f;
  for (int i = 0; i < TEXTL; ++i) s += h[((size_t)b*SEQL + i)*DIM + c];
  tm[b*DIM + c] = s * (1.f/TEXTL);
}

// ---------------- cond = silu(temb+tm) @ w_cond + b_cond (fp32 exact) -------
__global__ __launch_bounds__(256)
void k_cond(const float* __restrict__ temb, const float* __restrict__ tm,
            const float* __restrict__ w_cond, const float* __restrict__ b_cond,
            float* __restrict__ cond){
  __shared__ float st[2*DIM];
  __shared__ float red[4][2][64];
  const int t = threadIdx.x;
  for (int i = t; i < 2*DIM; i += 256) st[i] = siluf(temb[i] + tm[i]);
  __syncthreads();
  const int tx = t & 63, ty = t >> 6;
  const int col = blockIdx.x*64 + tx;
  float a0 = 0.f, a1 = 0.f;
  for (int k = ty*768; k < ty*768 + 768; ++k){
    const float w = w_cond[(size_t)k*DIM + col];
    a0 += st[k]*w; a1 += st[DIM + k]*w;
  }
  red[ty][0][tx] = a0; red[ty][1][tx] = a1;
  __syncthreads();
  if (ty == 0){
    float s0 = red[0][0][tx] + red[1][0][tx] + red[2][0][tx] + red[3][0][tx];
    float s1 = red[0][1][tx] + red[1][1][tx] + red[2][1][tx] + red[3][1][tx];
    cond[col]       = s0 + b_cond[col];
    cond[DIM + col] = s1 + b_cond[col];
  }
}

// ---------------- mask[b,i] = ((img_h+cond)@w_sel + b_sel > 0) -------------
__global__ __launch_bounds__(256)
void k_sel(const float* __restrict__ h, const float* __restrict__ cond,
           const float* __restrict__ w_sel, const float* __restrict__ b_sel,
           float* __restrict__ maskb){
  const int lane = threadIdx.x & 63;
  const int wv = threadIdx.x >> 6;
  const int wid = blockIdx.x*4 + wv;          // 0..2047
  const int b = wid >> 10, i = wid & 1023;
  const float* hr = h + ((size_t)b*SEQL + TEXTL + i)*DIM;
  const float* cr = cond + (size_t)b*DIM;
  float acc = 0.f;
  #pragma unroll
  for (int j = 0; j < 12; ++j){
    const int c4 = j*64 + lane;
    float4 hv = ((const float4*)hr)[c4];
    float4 cv = ((const float4*)cr)[c4];
    float4 wv4 = ((const float4*)w_sel)[c4];
    acc += (hv.x+cv.x)*wv4.x + (hv.y+cv.y)*wv4.y + (hv.z+cv.z)*wv4.z + (hv.w+cv.w)*wv4.w;
  }
  #pragma unroll
  for (int off = 1; off < 64; off <<= 1) acc += __shfl_xor(acc, off, 64);
  if (lane == 0) maskb[wid] = (acc + b_sel[0]) > 0.f ? 1.f : 0.f;
}

// ---------------- layernorm + adaLN modulate -> x bf16 ---------------------
__global__ __launch_bounds__(256)
void k_lnmod(const float* __restrict__ h, const float* __restrict__ e,
             u16* __restrict__ xb){
  const int t = blockIdx.x;
  const int b = t / SEQL;
  const float* row = h + (size_t)t*DIM;
  float4 v[3];
  float s = 0.f, ss = 0.f;
  #pragma unroll
  for (int j = 0; j < 3; ++j){
    v[j] = ((const float4*)row)[threadIdx.x + j*256];
    s  += v[j].x + v[j].y + v[j].z + v[j].w;
    ss += v[j].x*v[j].x + v[j].y*v[j].y + v[j].z*v[j].z + v[j].w*v[j].w;
  }
  __shared__ float rs[4], rss[4];
  #pragma unroll
  for (int off = 1; off < 64; off <<= 1){
    s += __shfl_xor(s, off, 64); ss += __shfl_xor(ss, off, 64);
  }
  const int wv = threadIdx.x >> 6;
  if ((threadIdx.x & 63) == 0){ rs[wv] = s; rss[wv] = ss; }
  __syncthreads();
  s = rs[0]+rs[1]+rs[2]+rs[3]; ss = rss[0]+rss[1]+rss[2]+rss[3];
  const float mu = s * (1.f/DIM);
  const float var = ss * (1.f/DIM) - mu*mu;
  const float rstd = rsqrtf(var + EPSV);
  const float* sh = e + (size_t)b*9216;
  #pragma unroll
  for (int j = 0; j < 3; ++j){
    const int i4 = threadIdx.x + j*256;
    float4 sf = ((const float4*)sh)[i4];
    float4 sc = ((const float4*)(sh + DIM))[i4];
    ushort4 o;
    o.x = f2bf(((v[j].x - mu)*rstd)*(1.f + sc.x) + sf.x);
    o.y = f2bf(((v[j].y - mu)*rstd)*(1.f + sc.y) + sf.y);
    o.z = f2bf(((v[j].z - mu)*rstd)*(1.f + sc.z) + sf.z);
    o.w = f2bf(((v[j].w - mu)*rstd)*(1.f + sc.w) + sf.w);
    ((ushort4*)(xb + (size_t)t*DIM))[i4] = o;
  }
}

// ---------------- 128x128 bf16 MFMA GEMM, C = A @ BT^T (+epilogue) ----------
// A: [M][K] bf16, BT: [N][K] bf16 (pre-transposed weight).
// MODE 0: Cf[row*ldc+col] = acc + bias[col]                (QKV, z-batched)
// MODE 1: Cb[row*ldc+col_off+col] = bf16(gelu(acc+bias))   (MLP1 -> concat)
// MODE 2: Cf = residual + gate*( (acc+bias) * mask )       (final out)
template<int MODE>
__global__ __launch_bounds__(256, 2)
void k_gemm(const u16* __restrict__ A, const u16* __restrict__ BT,
            const float* __restrict__ bias,
            float* __restrict__ Cf, u16* __restrict__ Cb,
            int K, int ldc, int col_off,
            size_t zsB, size_t zsC, size_t zsBias,
            const float* __restrict__ residual, const float* __restrict__ egate,
            const float* __restrict__ maskb){
  __shared__ __align__(16) u16 As[128*32];
  __shared__ __align__(16) u16 Bs[128*32];
  const int tid  = threadIdx.x;
  const int lane = tid & 63;
  const int wv   = tid >> 6;
  const int wr   = wv >> 1, wc = wv & 1;
  const int brow = blockIdx.y * 128, bcol = blockIdx.x * 128;
  const int l16 = lane & 15;
  const int g4  = lane >> 4;
  BT   += blockIdx.z * zsB;
  bias += blockIdx.z * zsBias;

  f32x4 acc[4][4] = {};
  const int nkt = K >> 5;
  for (int kt = 0; kt < nkt; ++kt){
    __syncthreads();
    #pragma unroll
    for (int c = 0; c < 2; ++c){
      const int Lb = wv*2048 + c*1024;
      const int row = (Lb + lane*16) >> 6;
      const int sch = (lane & 3) ^ ((row >> 1) & 3);   // XOR swizzle (conflict-free reads)
      ld_lds16(A + (size_t)(brow + row)*K + kt*32 + sch*8, (char*)As + Lb);
    }
    #pragma unroll
    for (int c = 0; c < 2; ++c){
      const int Lb = wv*2048 + c*1024;
      const int row = (Lb + lane*16) >> 6;
      const int sch = (lane & 3) ^ ((row >> 1) & 3);
      ld_lds16(BT + (size_t)(bcol + row)*K + kt*32 + sch*8, (char*)Bs + Lb);
    }
    __syncthreads();
    bf16x8 af[4], bfr[4];
    #pragma unroll
    for (int m = 0; m < 4; ++m){
      const int row = wr*64 + m*16 + l16;
      const int sch = g4 ^ ((row >> 1) & 3);
      af[m] = *(const bf16x8*)((const char*)As + row*64 + sch*16);
    }
    #pragma unroll
    for (int n = 0; n < 4; ++n){
      const int row = wc*64 + n*16 + l16;
      const int sch = g4 ^ ((row >> 1) & 3);
      bfr[n] = *(const bf16x8*)((const char*)Bs + row*64 + sch*16);
    }
    #pragma unroll
    for (int m = 0; m < 4; ++m)
      #pragma unroll
      for (int n = 0; n < 4; ++n)
        acc[m][n] = __builtin_amdgcn_mfma_f32_16x16x32_bf16(af[m], bfr[n], acc[m][n], 0, 0, 0);
  }
  float* Cfz = Cf + blockIdx.z * zsC;
  #pragma unroll
  for (int m = 0; m < 4; ++m){
    #pragma unroll
    for (int n = 0; n < 4; ++n){
      #pragma unroll
      for (int r = 0; r < 4; ++r){
        const int row = brow + wr*64 + m*16 + g4*4 + r;   // C/D: row=(lane>>4)*4+reg
        const int col = bcol + wc*64 + n*16 + l16;        //      col=lane&15
        const float val = acc[m][n][r] + bias[col];
        if (MODE == 0){
          Cfz[(size_t)row*ldc + col] = val;
        } else if (MODE == 1){
          Cb[(size_t)row*ldc + col_off + col] = f2bf(geluf(val));
        } else {
          const int bb = row / SEQL;
          const int sidx = row - bb*SEQL;
          const float mk = (sidx < TEXTL) ? 1.f : maskb[bb*IMGL + sidx - TEXTL];
          Cfz[(size_t)row*ldc + col] = residual[(size_t)row*DIM + col]
                                     + egate[(size_t)bb*9216 + 2*DIM + col] * (val * mk);
        }
      }
    }
  }
}

// ---------------- q/k: rmsnorm + rope -> bf16 -------------------------------
__global__ __launch_bounds__(256)
void k_qkpost(const float* __restrict__ qkv, const float* __restrict__ rcos,
              const float* __restrict__ rsin, const float* __restrict__ qscale,
              const float* __restrict__ kscale, u16* __restrict__ qb,
              u16* __restrict__ kb){
  const int t = blockIdx.x;
  const int which = blockIdx.y;
  const float* src = qkv + ((size_t)which*NTOK + t)*DIM;
  const float* gvec = which == 0 ? qscale : kscale;
  u16* dst = which == 0 ? qb : kb;
  const int s = t % SEQL;
  const int lane = threadIdx.x & 63;
  const int wv = threadIdx.x >> 6;
  const int l32 = lane & 31;
  const int hh = lane >> 5;
  #pragma unroll
  for (int p = 0; p < 3; ++p){
    const int hidx = p*8 + wv*2 + hh;
    float4 v = ((const float4*)(src + hidx*HD))[l32];
    float ssq = v.x*v.x + v.y*v.y + v.z*v.z + v.w*v.w;
    #pragma unroll
    for (int off = 1; off < 32; off <<= 1) ssq += __shfl_xor(ssq, off, 64);
    const float rms = rsqrtf(ssq * (1.f/HD) + EPSV);
    const int d0 = l32*4;
    const float t0 = v.x*rms*gvec[d0],   t1 = v.y*rms*gvec[d0+1];
    const float t2 = v.z*rms*gvec[d0+2], t3 = v.w*rms*gvec[d0+3];
    const int i0 = l32*2;
    const float c0 = rcos[s*64 + i0],   s0 = rsin[s*64 + i0];
    const float c1 = rcos[s*64 + i0+1], s1 = rsin[s*64 + i0+1];
    ushort4 o;
    o.x = f2bf(t0*c0 - t1*s0);
    o.y = f2bf(t0*s0 + t1*c0);
    o.z = f2bf(t2*c1 - t3*s1);
    o.w = f2bf(t2*s1 + t3*c1);
    ((ushort4*)(dst + (size_t)t*DIM + hidx*HD))[l32] = o;
  }
}

// ---------------- v -> vt bf16 [bh][d][s] (transposed for PV B-operand) -----
__global__ __launch_bounds__(256)
void k_vpost(const float* __restrict__ qkv, u16* __restrict__ vt){
  __shared__ float tile[64][65];
  const int bh = blockIdx.x;
  const int st = blockIdx.y;
  const int dt = blockIdx.z;
  const int b = bh / NHEADS, hidx = bh % NHEADS;
  const float* v = qkv + (size_t)2*NTOK*DIM;
  const int tx = threadIdx.x & 63, ty = threadIdx.x >> 6;
  #pragma unroll
  for (int i = 0; i < 16; ++i){
    const int r = ty + i*4;
    tile[r][tx] = v[((size_t)b*SEQL + st*64 + r)*DIM + hidx*HD + dt*64 + tx];
  }
  __syncthreads();
  #pragma unroll
  for (int i = 0; i < 16; ++i){
    const int r = ty + i*4;
    vt[((size_t)bh*HD + dt*64 + r)*SEQL + st*64 + tx] = f2bf(tile[tx][r]);
  }
}

// ---------------- flash attention (64-row q tiles, 64-key steps) ------------
__global__ __launch_bounds__(256, 2)
void k_attn(const u16* __restrict__ q, const u16* __restrict__ kg,
            const u16* __restrict__ vt, u16* __restrict__ cat){
  __shared__ __align__(16) u16 Ks[64*128];   // [key][d], swizzled
  __shared__ __align__(16) u16 Vs[128*64];   // [d][key], swizzled
  __shared__ __align__(16) u16 Ps[4*16*64];  // per-wave P, swizzled
  const int lane = threadIdx.x & 63;
  const int wv = threadIdx.x >> 6;
  const int bh = blockIdx.y, b = bh / NHEADS, hidx = bh % NHEADS;
  const int qt = blockIdx.x;
  const int l16 = lane & 15;
  const int g4 = lane >> 4;

  bf16x8 qf[4];
  {
    const int qrow = qt*64 + wv*16 + l16;
    const u16* qptr = q + ((size_t)b*SEQL + qrow)*DIM + hidx*HD;
    #pragma unroll
    for (int ksi = 0; ksi < 4; ++ksi)
      qf[ksi] = *(const bf16x8*)(qptr + ksi*32 + g4*8);
  }
  f32x4 out[8] = {};
  float mreg[4] = {-1e30f, -1e30f, -1e30f, -1e30f};
  float lreg[4] = {0.f, 0.f, 0.f, 0.f};
  const float scl = 0.08838834764831845f;  // 1/sqrt(128)

  for (int kt = 0; kt < SEQL/64; ++kt){
    __syncthreads();
    #pragma unroll
    for (int c = 0; c < 4; ++c){            // stage K tile: 16KB
      const int Lb = wv*4096 + c*1024;
      const int row = (Lb + lane*16) >> 8;
      const int sch = (lane & 15) ^ (row & 7);
      ld_lds16(kg + ((size_t)b*SEQL + kt*64 + row)*DIM + hidx*HD + sch*8, (char*)Ks + Lb);
    }
    #pragma unroll
    for (int c = 0; c < 4; ++c){            // stage V tile: 16KB
      const int Lb = wv*4096 + c*1024;
      const int row = (Lb + lane*16) >> 7;
      const int sch = (lane & 7) ^ (row & 7);
      ld_lds16(vt + ((size_t)bh*HD + row)*SEQL + kt*64 + sch*8, (char*)Vs + Lb);
    }
    __syncthreads();
    // S = Q K^T (rows=q via D-layout, cols=key)
    f32x4 sf[4];
    #pragma unroll
    for (int kc = 0; kc < 4; ++kc){
      sf[kc] = (f32x4){0.f, 0.f, 0.f, 0.f};
      #pragma unroll
      for (int ksi = 0; ksi < 4; ++ksi){
        const int key = kc*16 + l16;
        const int c0 = ksi*4 + g4;
        const int sch = c0 ^ (key & 7);
        bf16x8 kbf = *(const bf16x8*)((const char*)Ks + key*256 + sch*16);
        sf[kc] = __builtin_amdgcn_mfma_f32_16x16x32_bf16(qf[ksi], kbf, sf[kc], 0, 0, 0);
      }
    }
    #pragma unroll
    for (int kc = 0; kc < 4; ++kc) sf[kc] *= scl;
    // online softmax per q-row (rows live on 16-lane groups)
    #pragma unroll
    for (int r = 0; r < 4; ++r){
      float mx = fmaxf(fmaxf(sf[0][r], sf[1][r]), fmaxf(sf[2][r], sf[3][r]));
      #pragma unroll
      for (int off = 1; off < 16; off <<= 1) mx = fmaxf(mx, __shfl_xor(mx, off, 64));
      const float mnew = fmaxf(mreg[r], mx);
      const float sfac = __expf(mreg[r] - mnew);
      mreg[r] = mnew;
      float rsum = 0.f;
      #pragma unroll
      for (int kc = 0; kc < 4; ++kc){
        const float p = __expf(sf[kc][r] - mnew);
        sf[kc][r] = p;
        rsum += p;
      }
      #pragma unroll
      for (int off = 1; off < 16; off <<= 1) rsum += __shfl_xor(rsum, off, 64);
      lreg[r] = lreg[r]*sfac + rsum;
      #pragma unroll
      for (int nc = 0; nc < 8; ++nc) out[nc][r] *= sfac;
    }
    // P -> LDS (bf16, swizzled) for A-operand relayout
    #pragma unroll
    for (int kc = 0; kc < 4; ++kc){
      #pragma unroll
      for (int r = 0; r < 4; ++r){
        const int prow = g4*4 + r;
        int byte = prow*128 + (kc*16 + l16)*2;
        byte ^= (prow & 7) << 4;
        *(u16*)((char*)Ps + wv*2048 + byte) = f2bf(sf[kc][r]);
      }
    }
    __syncthreads();
    // out += P @ V
    bf16x8 pa[2];
    #pragma unroll
    for (int k2 = 0; k2 < 2; ++k2){
      const int prow = l16;
      const int c0 = k2*4 + g4;
      const int sch = c0 ^ (prow & 7);
      pa[k2] = *(const bf16x8*)((const char*)Ps + wv*2048 + prow*128 + sch*16);
    }
    #pragma unroll
    for (int nc = 0; nc < 8; ++nc){
      #pragma unroll
      for (int k2 = 0; k2 < 2; ++k2){
        const int d = nc*16 + l16;
        const int c0 = k2*4 + g4;
        const int sch = c0 ^ (d & 7);
        bf16x8 vb = *(const bf16x8*)((const char*)Vs + d*128 + sch*16);
        out[nc] = __builtin_amdgcn_mfma_f32_16x16x32_bf16(pa[k2], vb, out[nc], 0, 0, 0);
      }
    }
  }
  #pragma unroll
  for (int nc = 0; nc < 8; ++nc){
    #pragma unroll
    for (int r = 0; r < 4; ++r){
      const int qrow = qt*64 + wv*16 + g4*4 + r;
      const int d = nc*16 + l16;
      cat[((size_t)b*SEQL + qrow)*CATK + hidx*HD + d] = f2bf(out[nc][r] / lreg[r]);
    }
  }
}

// ---------------------------------------------------------------------------
extern "C" void kernel_launch(void* const* d_in, const int* in_sizes, int n_in,
                              void* d_out, int out_size, void* d_ws, size_t ws_size,
                              hipStream_t stream){
  const float* hid    = (const float*)d_in[0];
  const float* temb   = (const float*)d_in[1];
  const float* rcos   = (const float*)d_in[2];
  const float* rsin   = (const float*)d_in[3];
  const float* w_ada  = (const float*)d_in[4];
  const float* b_ada  = (const float*)d_in[5];
  const float* wq     = (const float*)d_in[6];
  const float* bq     = (const float*)d_in[7];
  const float* wk     = (const float*)d_in[8];
  const float* bk     = (const float*)d_in[9];
  const float* wvw    = (const float*)d_in[10];
  const float* bv     = (const float*)d_in[11];
  const float* qs     = (const float*)d_in[12];
  const float* ksc    = (const float*)d_in[13];
  const float* w_cond = (const float*)d_in[14];
  const float* b_cond = (const float*)d_in[15];
  const float* w_sel  = (const float*)d_in[16];
  const float* b_sel  = (const float*)d_in[17];
  const float* w1     = (const float*)d_in[18];
  const float* b1     = (const float*)d_in[19];
  const float* w2     = (const float*)d_in[20];
  const float* b2     = (const float*)d_in[21];
  float* outp = (float*)d_out;

  // ---- workspace layout (~252 MB total) ----
  // wT: shared just-in-time transposed-weight buffer, sized for the largest
  //     weight (w2: DIM x CATK = 47.2M elems). Reused: wqkv -> w1 -> w2.
  // qkvF: fp32 QKV output [3][NTOK][DIM] (94.4 MB); DEAD after k_qkpost/k_vpost,
  //     then its storage is reused as `cat` (bf16 [NTOK][CATK], 78.6 MB).
  char* ws = (char*)d_ws;
  u16* wT     = (u16*)ws;                                  // 47.2M u16 = 94.4 MB
  u16* xb     = wT + (size_t)DIM*CATK;                     // [NTOK][DIM] bf16
  float* qkvF = (float*)(xb + (size_t)NTOK*DIM);           // [3][NTOK][DIM] f32
  u16* cat    = (u16*)qkvF;                                // alias (qkvF dead by then)
  u16* qb     = (u16*)(qkvF + (size_t)3*NTOK*DIM);         // [NTOK][DIM] bf16
  u16* kbb    = qb + (size_t)NTOK*DIM;                     // [NTOK][DIM] bf16
  u16* vtb    = kbb + (size_t)NTOK*DIM;                    // [48][HD][SEQL] bf16
  float* e    = (float*)(vtb + (size_t)NB*NHEADS*HD*SEQL); // [NB][9216]
  float* tm   = e + NB*9216;                               // [NB][DIM]
  float* cond = tm + NB*DIM;                               // [NB][DIM]
  float* maskb= cond + NB*DIM;                             // [NB*IMGL]
  float* bcat = maskb + NB*IMGL;                           // [3*DIM]

  dim3 blk(256);
  // small prep (independent of weights)
  k_cat3<<<dim3(36), blk, 0, stream>>>(bq, bk, bv, bcat);
  k_ada<<<dim3(144), blk, 0, stream>>>(temb, w_ada, b_ada, e);
  k_tmean<<<dim3(12,2), blk, 0, stream>>>(hid, tm);
  k_cond<<<dim3(48), blk, 0, stream>>>(temb, tm, w_cond, b_cond, cond);
  k_sel<<<dim3(512), blk, 0, stream>>>(hid, cond, w_sel, b_sel, maskb);
  k_lnmod<<<dim3(NTOK), blk, 0, stream>>>(hid, e, xb);
  // --- stage 1: QKV ---
  k_transpose_cvt<<<dim3(48,48),  blk, 0, stream>>>(wq,  wT,                     DIM, DIM);
  k_transpose_cvt<<<dim3(48,48),  blk, 0, stream>>>(wk,  wT + (size_t)DIM*DIM,   DIM, DIM);
  k_transpose_cvt<<<dim3(48,48),  blk, 0, stream>>>(wvw, wT + (size_t)2*DIM*DIM, DIM, DIM);
  k_gemm<0><<<dim3(24,20,3), blk, 0, stream>>>(xb, wT, bcat, qkvF, (u16*)nullptr,
      DIM, DIM, 0, (size_t)DIM*DIM, (size_t)NTOK*DIM, (size_t)DIM,
      nullptr, nullptr, nullptr);
  k_qkpost<<<dim3(NTOK,2), blk, 0, stream>>>(qkvF, rcos, rsin, qs, ksc, qb, kbb);
  k_vpost<<<dim3(48,20,2), blk, 0, stream>>>(qkvF, vtb);
  // qkvF is now dead; its storage becomes `cat`.
  // attention -> cat[:, 0:3072]
  k_attn<<<dim3(20,48), blk, 0, stream>>>(qb, kbb, vtb, cat);
  // --- stage 2: MLP1 (gelu) -> cat[:, 3072:] ---
  k_transpose_cvt<<<dim3(192,48), blk, 0, stream>>>(w1, wT, DIM, MLPD);
  k_gemm<1><<<dim3(96,20), blk, 0, stream>>>(xb, wT, b1, (float*)nullptr, cat,
      DIM, CATK, DIM, 0, 0, 0, nullptr, nullptr, nullptr);
  // --- stage 3: W2 + mask*gate*residual -> out ---
  k_transpose_cvt<<<dim3(48,240), blk, 0, stream>>>(w2, wT, CATK, DIM);
  k_gemm<2><<<dim3(24,20), blk, 0, stream>>>(cat, wT, b2, outp, (u16*)nullptr,
      CATK, DIM, 0, 0, 0, 0, hid, e, maskb);
}

// Round 6
// 1681.099 us; speedup vs baseline: 1.0110x; 1.0110x over previous
//
#include <hip/hip_runtime.h>
#include <hip/hip_bf16.h>

// FluxSingleTransformerBlock forward, MI355X.
// R4 -> R5: W2 gemm split-K=4 (atomic accum + epilogue kernel) to fix measured
// occupancy starvation (480 blocks, 21.5% occ, 25% MfmaUtil); all GEMMs get
// double-buffered LDS staging (prefetch next K-tile before MFMA, 1 barrier/step).

#define DIM    3072
#define NHEADS 24
#define HD     128
#define MLPD   12288
#define NB     2
#define TEXTL  256
#define IMGL   1024
#define SEQL   1280
#define NTOK   (NB*SEQL)
#define CATK   (DIM+MLPD)
#define EPSV   1e-6f
#define WSPLIT 4

typedef unsigned short u16;
typedef __bf16 bf16x8 __attribute__((ext_vector_type(8)));
typedef float f32x4 __attribute__((ext_vector_type(4)));

__device__ __forceinline__ u16 f2bf(float f){
  unsigned u = __builtin_bit_cast(unsigned, f);
  u += 0x7fffu + ((u >> 16) & 1u);
  return (u16)(u >> 16);
}
__device__ __forceinline__ float siluf(float x){ return x / (1.f + __expf(-x)); }
__device__ __forceinline__ float geluf(float x){
  float t = 0.7978845608028654f * (x + 0.044715f * x * x * x);
  float th = 1.f - 2.f / (__expf(2.f * t) + 1.f);
  return 0.5f * x * (1.f + th);
}
__device__ __forceinline__ void ld_lds16(const void* g, void* l){
  __builtin_amdgcn_global_load_lds((const __attribute__((address_space(1))) void*)g,
                                   (__attribute__((address_space(3))) void*)l, 16, 0, 0);
}

// ---------------- weight fp32 -> bf16 transpose: W[K][N] -> WT[N][K] --------
__global__ __launch_bounds__(256)
void k_transpose_cvt(const float* __restrict__ W, u16* __restrict__ WT, int K, int N){
  __shared__ float tile[64][65];
  const int n0 = blockIdx.x * 64, k0 = blockIdx.y * 64;
  const int tx = threadIdx.x & 63, ty = threadIdx.x >> 6;
  #pragma unroll
  for (int i = 0; i < 16; ++i){
    const int r = ty + i*4;
    tile[r][tx] = W[(size_t)(k0 + r)*N + n0 + tx];
  }
  __syncthreads();
  #pragma unroll
  for (int i = 0; i < 16; ++i){
    const int r = ty + i*4;
    WT[(size_t)(n0 + r)*K + k0 + tx] = f2bf(tile[tx][r]);
  }
}

// ---------------- bias concat for batched QKV gemm --------------------------
__global__ void k_cat3(const float* __restrict__ a, const float* __restrict__ b,
                       const float* __restrict__ c, float* __restrict__ o){
  const int i = blockIdx.x*256 + threadIdx.x;
  if (i < DIM) o[i] = a[i];
  else if (i < 2*DIM) o[i] = b[i - DIM];
  else o[i] = c[i - 2*DIM];
}

// ---------------- zero fill (accumulator init; no memset in graph capture) --
__global__ void k_zero(float* __restrict__ p, int n4){
  const int i = blockIdx.x*256 + threadIdx.x;
  if (i < n4) ((float4*)p)[i] = make_float4(0.f,0.f,0.f,0.f);
}

// ---------------- e = silu(temb) @ w_ada + b_ada  (both batches) ------------
__global__ __launch_bounds__(256)
void k_ada(const float* __restrict__ temb, const float* __restrict__ w_ada,
           const float* __restrict__ b_ada, float* __restrict__ e){
  __shared__ float st[2*DIM];
  __shared__ float red[4][2][64];
  const int t = threadIdx.x;
  for (int i = t; i < 2*DIM; i += 256) st[i] = siluf(temb[i]);
  __syncthreads();
  const int tx = t & 63, ty = t >> 6;
  const int col = blockIdx.x*64 + tx;
  float a0 = 0.f, a1 = 0.f;
  for (int k = ty*768; k < ty*768 + 768; ++k){
    const float w = w_ada[(size_t)k*9216 + col];
    a0 += st[k]*w; a1 += st[DIM + k]*w;
  }
  red[ty][0][tx] = a0; red[ty][1][tx] = a1;
  __syncthreads();
  if (ty == 0){
    float s0 = red[0][0][tx] + red[1][0][tx] + red[2][0][tx] + red[3][0][tx];
    float s1 = red[0][1][tx] + red[1][1][tx] + red[2][1][tx] + red[3][1][tx];
    e[col]        = s0 + b_ada[col];
    e[9216 + col] = s1 + b_ada[col];
  }
}

// ---------------- tm[b,c] = mean over text tokens of hidden ----------------
__global__ void k_tmean(const float* __restrict__ h, float* __restrict__ tm){
  const int b = blockIdx.y;
  const int c = blockIdx.x*256 + threadIdx.x;
  float s = 0.f;
  for (int i = 0; i < TEXTL; ++i) s += h[((size_t)b*SEQL + i)*DIM + c];
  tm[b*DIM + c] = s * (1.f/TEXTL);
}

// ---------------- cond = silu(temb+tm) @ w_cond + b_cond (fp32 exact) -------
__global__ __launch_bounds__(256)
void k_cond(const float* __restrict__ temb, const float* __restrict__ tm,
            const float* __restrict__ w_cond, const float* __restrict__ b_cond,
            float* __restrict__ cond){
  __shared__ float st[2*DIM];
  __shared__ float red[4][2][64];
  const int t = threadIdx.x;
  for (int i = t; i < 2*DIM; i += 256) st[i] = siluf(temb[i] + tm[i]);
  __syncthreads();
  const int tx = t & 63, ty = t >> 6;
  const int col = blockIdx.x*64 + tx;
  float a0 = 0.f, a1 = 0.f;
  for (int k = ty*768; k < ty*768 + 768; ++k){
    const float w = w_cond[(size_t)k*DIM + col];
    a0 += st[k]*w; a1 += st[DIM + k]*w;
  }
  red[ty][0][tx] = a0; red[ty][1][tx] = a1;
  __syncthreads();
  if (ty == 0){
    float s0 = red[0][0][tx] + red[1][0][tx] + red[2][0][tx] + red[3][0][tx];
    float s1 = red[0][1][tx] + red[1][1][tx] + red[2][1][tx] + red[3][1][tx];
    cond[col]       = s0 + b_cond[col];
    cond[DIM + col] = s1 + b_cond[col];
  }
}

// ---------------- mask[b,i] = ((img_h+cond)@w_sel + b_sel > 0) -------------
__global__ __launch_bounds__(256)
void k_sel(const float* __restrict__ h, const float* __restrict__ cond,
           const float* __restrict__ w_sel, const float* __restrict__ b_sel,
           float* __restrict__ maskb){
  const int lane = threadIdx.x & 63;
  const int wv = threadIdx.x >> 6;
  const int wid = blockIdx.x*4 + wv;          // 0..2047
  const int b = wid >> 10, i = wid & 1023;
  const float* hr = h + ((size_t)b*SEQL + TEXTL + i)*DIM;
  const float* cr = cond + (size_t)b*DIM;
  float acc = 0.f;
  #pragma unroll
  for (int j = 0; j < 12; ++j){
    const int c4 = j*64 + lane;
    float4 hv = ((const float4*)hr)[c4];
    float4 cv = ((const float4*)cr)[c4];
    float4 wv4 = ((const float4*)w_sel)[c4];
    acc += (hv.x+cv.x)*wv4.x + (hv.y+cv.y)*wv4.y + (hv.z+cv.z)*wv4.z + (hv.w+cv.w)*wv4.w;
  }
  #pragma unroll
  for (int off = 1; off < 64; off <<= 1) acc += __shfl_xor(acc, off, 64);
  if (lane == 0) maskb[wid] = (acc + b_sel[0]) > 0.f ? 1.f : 0.f;
}

// ---------------- layernorm + adaLN modulate -> x bf16 ---------------------
__global__ __launch_bounds__(256)
void k_lnmod(const float* __restrict__ h, const float* __restrict__ e,
             u16* __restrict__ xb){
  const int t = blockIdx.x;
  const int b = t / SEQL;
  const float* row = h + (size_t)t*DIM;
  float4 v[3];
  float s = 0.f, ss = 0.f;
  #pragma unroll
  for (int j = 0; j < 3; ++j){
    v[j] = ((const float4*)row)[threadIdx.x + j*256];
    s  += v[j].x + v[j].y + v[j].z + v[j].w;
    ss += v[j].x*v[j].x + v[j].y*v[j].y + v[j].z*v[j].z + v[j].w*v[j].w;
  }
  __shared__ float rs[4], rss[4];
  #pragma unroll
  for (int off = 1; off < 64; off <<= 1){
    s += __shfl_xor(s, off, 64); ss += __shfl_xor(ss, off, 64);
  }
  const int wv = threadIdx.x >> 6;
  if ((threadIdx.x & 63) == 0){ rs[wv] = s; rss[wv] = ss; }
  __syncthreads();
  s = rs[0]+rs[1]+rs[2]+rs[3]; ss = rss[0]+rss[1]+rss[2]+rss[3];
  const float mu = s * (1.f/DIM);
  const float var = ss * (1.f/DIM) - mu*mu;
  const float rstd = rsqrtf(var + EPSV);
  const float* sh = e + (size_t)b*9216;
  #pragma unroll
  for (int j = 0; j < 3; ++j){
    const int i4 = threadIdx.x + j*256;
    float4 sf = ((const float4*)sh)[i4];
    float4 sc = ((const float4*)(sh + DIM))[i4];
    ushort4 o;
    o.x = f2bf(((v[j].x - mu)*rstd)*(1.f + sc.x) + sf.x);
    o.y = f2bf(((v[j].y - mu)*rstd)*(1.f + sc.y) + sf.y);
    o.z = f2bf(((v[j].z - mu)*rstd)*(1.f + sc.z) + sf.z);
    o.w = f2bf(((v[j].w - mu)*rstd)*(1.f + sc.w) + sf.w);
    ((ushort4*)(xb + (size_t)t*DIM))[i4] = o;
  }
}

// ---------------- 128x128 bf16 MFMA GEMM (double-buffered staging) ----------
// A: [M][Kstride] bf16, BT: [N][Kstride] bf16.
// MODE 0: Cf[z][row][col] = acc + bias[col]               (QKV, z-batched)
// MODE 1: Cb[row][col_off+col] = bf16(gelu(acc+bias))     (MLP1 -> concat)
// MODE 2: Cf = residual + gate*((acc+bias)*mask)          (fused out, unused now)
// MODE 3: atomicAdd(Cf[row][col], acc)                    (split-K partial, z=K-chunk)
template<int MODE>
__global__ __launch_bounds__(256, 2)
void k_gemm(const u16* __restrict__ A, const u16* __restrict__ BT,
            const float* __restrict__ bias,
            float* __restrict__ Cf, u16* __restrict__ Cb,
            int Kstride, int Kloop, int ldc, int col_off,
            size_t zsB, size_t zsC, size_t zsBias,
            const float* __restrict__ residual, const float* __restrict__ egate,
            const float* __restrict__ maskb){
  __shared__ __align__(16) u16 As[2][128*32];
  __shared__ __align__(16) u16 Bs[2][128*32];
  const int tid  = threadIdx.x;
  const int lane = tid & 63;
  const int wv   = tid >> 6;
  const int wr   = wv >> 1, wc = wv & 1;
  const int brow = blockIdx.y * 128, bcol = blockIdx.x * 128;
  const int l16 = lane & 15;
  const int g4  = lane >> 4;
  size_t koff = 0;
  if (MODE == 3){
    koff = (size_t)blockIdx.z * Kloop;       // K-chunk offset
  } else {
    BT   += blockIdx.z * zsB;
    bias += blockIdx.z * zsBias;
  }
  const u16* Ab = A  + koff;
  const u16* Bb = BT + koff;

  auto stage = [&](int buf, int kt){
    #pragma unroll
    for (int c = 0; c < 2; ++c){
      const int Lb = wv*2048 + c*1024;
      const int row = (Lb + lane*16) >> 6;
      const int sch = (lane & 3) ^ ((row >> 1) & 3);   // XOR swizzle (conflict-free reads)
      ld_lds16(Ab + (size_t)(brow + row)*Kstride + kt*32 + sch*8, (char*)As[buf] + Lb);
    }
    #pragma unroll
    for (int c = 0; c < 2; ++c){
      const int Lb = wv*2048 + c*1024;
      const int row = (Lb + lane*16) >> 6;
      const int sch = (lane & 3) ^ ((row >> 1) & 3);
      ld_lds16(Bb + (size_t)(bcol + row)*Kstride + kt*32 + sch*8, (char*)Bs[buf] + Lb);
    }
  };

  f32x4 acc[4][4] = {};
  const int nkt = Kloop >> 5;
  stage(0, 0);
  __syncthreads();                    // hipcc drains vmcnt(0) before barrier
  int buf = 0;
  for (int kt = 0; kt < nkt; ++kt){
    if (kt + 1 < nkt) stage(buf ^ 1, kt + 1);   // prefetch next tile (in flight during MFMA)
    bf16x8 af[4], bfr[4];
    #pragma unroll
    for (int m = 0; m < 4; ++m){
      const int row = wr*64 + m*16 + l16;
      const int sch = g4 ^ ((row >> 1) & 3);
      af[m] = *(const bf16x8*)((const char*)As[buf] + row*64 + sch*16);
    }
    #pragma unroll
    for (int n = 0; n < 4; ++n){
      const int row = wc*64 + n*16 + l16;
      const int sch = g4 ^ ((row >> 1) & 3);
      bfr[n] = *(const bf16x8*)((const char*)Bs[buf] + row*64 + sch*16);
    }
    #pragma unroll
    for (int m = 0; m < 4; ++m)
      #pragma unroll
      for (int n = 0; n < 4; ++n)
        acc[m][n] = __builtin_amdgcn_mfma_f32_16x16x32_bf16(af[m], bfr[n], acc[m][n], 0, 0, 0);
    __syncthreads();                  // next tile staged & buf free for overwrite
    buf ^= 1;
  }
  float* Cfz = (MODE == 3) ? Cf : (Cf + blockIdx.z * zsC);
  #pragma unroll
  for (int m = 0; m < 4; ++m){
    #pragma unroll
    for (int n = 0; n < 4; ++n){
      #pragma unroll
      for (int r = 0; r < 4; ++r){
        const int row = brow + wr*64 + m*16 + g4*4 + r;   // C/D: row=(lane>>4)*4+reg
        const int col = bcol + wc*64 + n*16 + l16;        //      col=lane&15
        if (MODE == 3){
          atomicAdd(&Cfz[(size_t)row*ldc + col], acc[m][n][r]);
        } else {
          const float val = acc[m][n][r] + bias[col];
          if (MODE == 0){
            Cfz[(size_t)row*ldc + col] = val;
          } else if (MODE == 1){
            Cb[(size_t)row*ldc + col_off + col] = f2bf(geluf(val));
          } else {
            const int bb = row / SEQL;
            const int sidx = row - bb*SEQL;
            const float mk = (sidx < TEXTL) ? 1.f : maskb[bb*IMGL + sidx - TEXTL];
            Cfz[(size_t)row*ldc + col] = residual[(size_t)row*DIM + col]
                                       + egate[(size_t)bb*9216 + 2*DIM + col] * (val * mk);
          }
        }
      }
    }
  }
}

// ---------------- W2 split-K epilogue: out = res + gate*((acc+bias)*mask) ---
__global__ __launch_bounds__(256)
void k_w2epi(const float* __restrict__ accum, const float* __restrict__ bias,
             const float* __restrict__ residual, const float* __restrict__ egate,
             const float* __restrict__ maskb, float* __restrict__ out){
  const int row = blockIdx.x;
  const int bb = row / SEQL, sidx = row - bb*SEQL;
  const float mk = (sidx < TEXTL) ? 1.f : maskb[bb*IMGL + sidx - TEXTL];
  const float* ar = accum + (size_t)row*DIM;
  const float* rr = residual + (size_t)row*DIM;
  const float* gr = egate + (size_t)bb*9216 + 2*DIM;
  float* orow = out + (size_t)row*DIM;
  #pragma unroll
  for (int j = threadIdx.x; j < DIM/4; j += 256){
    float4 a = ((const float4*)ar)[j];
    float4 bv = ((const float4*)bias)[j];
    float4 r = ((const float4*)rr)[j];
    float4 g = ((const float4*)gr)[j];
    float4 o;
    o.x = r.x + g.x*((a.x + bv.x)*mk);
    o.y = r.y + g.y*((a.y + bv.y)*mk);
    o.z = r.z + g.z*((a.z + bv.z)*mk);
    o.w = r.w + g.w*((a.w + bv.w)*mk);
    ((float4*)orow)[j] = o;
  }
}

// ---------------- q/k: rmsnorm + rope -> bf16 -------------------------------
__global__ __launch_bounds__(256)
void k_qkpost(const float* __restrict__ qkv, const float* __restrict__ rcos,
              const float* __restrict__ rsin, const float* __restrict__ qscale,
              const float* __restrict__ kscale, u16* __restrict__ qb,
              u16* __restrict__ kb){
  const int t = blockIdx.x;
  const int which = blockIdx.y;
  const float* src = qkv + ((size_t)which*NTOK + t)*DIM;
  const float* gvec = which == 0 ? qscale : kscale;
  u16* dst = which == 0 ? qb : kb;
  const int s = t % SEQL;
  const int lane = threadIdx.x & 63;
  const int wv = threadIdx.x >> 6;
  const int l32 = lane & 31;
  const int hh = lane >> 5;
  #pragma unroll
  for (int p = 0; p < 3; ++p){
    const int hidx = p*8 + wv*2 + hh;
    float4 v = ((const float4*)(src + hidx*HD))[l32];
    float ssq = v.x*v.x + v.y*v.y + v.z*v.z + v.w*v.w;
    #pragma unroll
    for (int off = 1; off < 32; off <<= 1) ssq += __shfl_xor(ssq, off, 64);
    const float rms = rsqrtf(ssq * (1.f/HD) + EPSV);
    const int d0 = l32*4;
    const float t0 = v.x*rms*gvec[d0],   t1 = v.y*rms*gvec[d0+1];
    const float t2 = v.z*rms*gvec[d0+2], t3 = v.w*rms*gvec[d0+3];
    const int i0 = l32*2;
    const float c0 = rcos[s*64 + i0],   s0 = rsin[s*64 + i0];
    const float c1 = rcos[s*64 + i0+1], s1 = rsin[s*64 + i0+1];
    ushort4 o;
    o.x = f2bf(t0*c0 - t1*s0);
    o.y = f2bf(t0*s0 + t1*c0);
    o.z = f2bf(t2*c1 - t3*s1);
    o.w = f2bf(t2*s1 + t3*c1);
    ((ushort4*)(dst + (size_t)t*DIM + hidx*HD))[l32] = o;
  }
}

// ---------------- v -> vt bf16 [bh][d][s] (transposed for PV B-operand) -----
__global__ __launch_bounds__(256)
void k_vpost(const float* __restrict__ qkv, u16* __restrict__ vt){
  __shared__ float tile[64][65];
  const int bh = blockIdx.x;
  const int st = blockIdx.y;
  const int dt = blockIdx.z;
  const int b = bh / NHEADS, hidx = bh % NHEADS;
  const float* v = qkv + (size_t)2*NTOK*DIM;
  const int tx = threadIdx.x & 63, ty = threadIdx.x >> 6;
  #pragma unroll
  for (int i = 0; i < 16; ++i){
    const int r = ty + i*4;
    tile[r][tx] = v[((size_t)b*SEQL + st*64 + r)*DIM + hidx*HD + dt*64 + tx];
  }
  __syncthreads();
  #pragma unroll
  for (int i = 0; i < 16; ++i){
    const int r = ty + i*4;
    vt[((size_t)bh*HD + dt*64 + r)*SEQL + st*64 + tx] = f2bf(tile[tx][r]);
  }
}

// ---------------- flash attention (64-row q tiles, 64-key steps) ------------
__global__ __launch_bounds__(256, 2)
void k_attn(const u16* __restrict__ q, const u16* __restrict__ kg,
            const u16* __restrict__ vt, u16* __restrict__ cat){
  __shared__ __align__(16) u16 Ks[64*128];   // [key][d], swizzled
  __shared__ __align__(16) u16 Vs[128*64];   // [d][key], swizzled
  __shared__ __align__(16) u16 Ps[4*16*64];  // per-wave P, swizzled
  const int lane = threadIdx.x & 63;
  const int wv = threadIdx.x >> 6;
  const int bh = blockIdx.y, b = bh / NHEADS, hidx = bh % NHEADS;
  const int qt = blockIdx.x;
  const int l16 = lane & 15;
  const int g4 = lane >> 4;

  bf16x8 qf[4];
  {
    const int qrow = qt*64 + wv*16 + l16;
    const u16* qptr = q + ((size_t)b*SEQL + qrow)*DIM + hidx*HD;
    #pragma unroll
    for (int ksi = 0; ksi < 4; ++ksi)
      qf[ksi] = *(const bf16x8*)(qptr + ksi*32 + g4*8);
  }
  f32x4 out[8] = {};
  float mreg[4] = {-1e30f, -1e30f, -1e30f, -1e30f};
  float lreg[4] = {0.f, 0.f, 0.f, 0.f};
  const float scl = 0.08838834764831845f;  // 1/sqrt(128)

  for (int kt = 0; kt < SEQL/64; ++kt){
    __syncthreads();
    #pragma unroll
    for (int c = 0; c < 4; ++c){            // stage K tile: 16KB
      const int Lb = wv*4096 + c*1024;
      const int row = (Lb + lane*16) >> 8;
      const int sch = (lane & 15) ^ (row & 7);
      ld_lds16(kg + ((size_t)b*SEQL + kt*64 + row)*DIM + hidx*HD + sch*8, (char*)Ks + Lb);
    }
    #pragma unroll
    for (int c = 0; c < 4; ++c){            // stage V tile: 16KB
      const int Lb = wv*4096 + c*1024;
      const int row = (Lb + lane*16) >> 7;
      const int sch = (lane & 7) ^ (row & 7);
      ld_lds16(vt + ((size_t)bh*HD + row)*SEQL + kt*64 + sch*8, (char*)Vs + Lb);
    }
    __syncthreads();
    // S = Q K^T (rows=q via D-layout, cols=key)
    f32x4 sf[4];
    #pragma unroll
    for (int kc = 0; kc < 4; ++kc){
      sf[kc] = (f32x4){0.f, 0.f, 0.f, 0.f};
      #pragma unroll
      for (int ksi = 0; ksi < 4; ++ksi){
        const int key = kc*16 + l16;
        const int c0 = ksi*4 + g4;
        const int sch = c0 ^ (key & 7);
        bf16x8 kbf = *(const bf16x8*)((const char*)Ks + key*256 + sch*16);
        sf[kc] = __builtin_amdgcn_mfma_f32_16x16x32_bf16(qf[ksi], kbf, sf[kc], 0, 0, 0);
      }
    }
    #pragma unroll
    for (int kc = 0; kc < 4; ++kc) sf[kc] *= scl;
    // online softmax per q-row (rows live on 16-lane groups)
    #pragma unroll
    for (int r = 0; r < 4; ++r){
      float mx = fmaxf(fmaxf(sf[0][r], sf[1][r]), fmaxf(sf[2][r], sf[3][r]));
      #pragma unroll
      for (int off = 1; off < 16; off <<= 1) mx = fmaxf(mx, __shfl_xor(mx, off, 64));
      const float mnew = fmaxf(mreg[r], mx);
      const float sfac = __expf(mreg[r] - mnew);
      mreg[r] = mnew;
      float rsum = 0.f;
      #pragma unroll
      for (int kc = 0; kc < 4; ++kc){
        const float p = __expf(sf[kc][r] - mnew);
        sf[kc][r] = p;
        rsum += p;
      }
      #pragma unroll
      for (int off = 1; off < 16; off <<= 1) rsum += __shfl_xor(rsum, off, 64);
      lreg[r] = lreg[r]*sfac + rsum;
      #pragma unroll
      for (int nc = 0; nc < 8; ++nc) out[nc][r] *= sfac;
    }
    // P -> LDS (bf16, swizzled) for A-operand relayout
    #pragma unroll
    for (int kc = 0; kc < 4; ++kc){
      #pragma unroll
      for (int r = 0; r < 4; ++r){
        const int prow = g4*4 + r;
        int byte = prow*128 + (kc*16 + l16)*2;
        byte ^= (prow & 7) << 4;
        *(u16*)((char*)Ps + wv*2048 + byte) = f2bf(sf[kc][r]);
      }
    }
    __syncthreads();
    // out += P @ V
    bf16x8 pa[2];
    #pragma unroll
    for (int k2 = 0; k2 < 2; ++k2){
      const int prow = l16;
      const int c0 = k2*4 + g4;
      const int sch = c0 ^ (prow & 7);
      pa[k2] = *(const bf16x8*)((const char*)Ps + wv*2048 + prow*128 + sch*16);
    }
    #pragma unroll
    for (int nc = 0; nc < 8; ++nc){
      #pragma unroll
      for (int k2 = 0; k2 < 2; ++k2){
        const int d = nc*16 + l16;
        const int c0 = k2*4 + g4;
        const int sch = c0 ^ (d & 7);
        bf16x8 vb = *(const bf16x8*)((const char*)Vs + d*128 + sch*16);
        out[nc] = __builtin_amdgcn_mfma_f32_16x16x32_bf16(pa[k2], vb, out[nc], 0, 0, 0);
      }
    }
  }
  #pragma unroll
  for (int nc = 0; nc < 8; ++nc){
    #pragma unroll
    for (int r = 0; r < 4; ++r){
      const int qrow = qt*64 + wv*16 + g4*4 + r;
      const int d = nc*16 + l16;
      cat[((size_t)b*SEQL + qrow)*CATK + hidx*HD + d] = f2bf(out[nc][r] / lreg[r]);
    }
  }
}

// ---------------------------------------------------------------------------
extern "C" void kernel_launch(void* const* d_in, const int* in_sizes, int n_in,
                              void* d_out, int out_size, void* d_ws, size_t ws_size,
                              hipStream_t stream){
  const float* hid    = (const float*)d_in[0];
  const float* temb   = (const float*)d_in[1];
  const float* rcos   = (const float*)d_in[2];
  const float* rsin   = (const float*)d_in[3];
  const float* w_ada  = (const float*)d_in[4];
  const float* b_ada  = (const float*)d_in[5];
  const float* wq     = (const float*)d_in[6];
  const float* bq     = (const float*)d_in[7];
  const float* wk     = (const float*)d_in[8];
  const float* bk     = (const float*)d_in[9];
  const float* wvw    = (const float*)d_in[10];
  const float* bv     = (const float*)d_in[11];
  const float* qs     = (const float*)d_in[12];
  const float* ksc    = (const float*)d_in[13];
  const float* w_cond = (const float*)d_in[14];
  const float* b_cond = (const float*)d_in[15];
  const float* w_sel  = (const float*)d_in[16];
  const float* b_sel  = (const float*)d_in[17];
  const float* w1     = (const float*)d_in[18];
  const float* b1     = (const float*)d_in[19];
  const float* w2     = (const float*)d_in[20];
  const float* b2     = (const float*)d_in[21];
  float* outp = (float*)d_out;

  // ---- workspace layout (~252 MB total) ----
  char* ws = (char*)d_ws;
  u16* wT     = (u16*)ws;                                  // 47.2M u16 = 94.4 MB
  u16* xb     = wT + (size_t)DIM*CATK;                     // [NTOK][DIM] bf16
  float* qkvF = (float*)(xb + (size_t)NTOK*DIM);           // [3][NTOK][DIM] f32
  u16* cat    = (u16*)qkvF;                                // alias (qkvF dead by then)
  u16* qb     = (u16*)(qkvF + (size_t)3*NTOK*DIM);         // [NTOK][DIM] bf16
  u16* kbb    = qb + (size_t)NTOK*DIM;                     // [NTOK][DIM] bf16
  u16* vtb    = kbb + (size_t)NTOK*DIM;                    // [48][HD][SEQL] bf16
  float* accum= (float*)qb;                                // alias qb+kbb (31.46MB), dead after attn
  float* e    = (float*)(vtb + (size_t)NB*NHEADS*HD*SEQL); // [NB][9216]
  float* tm   = e + NB*9216;                               // [NB][DIM]
  float* cond = tm + NB*DIM;                               // [NB][DIM]
  float* maskb= cond + NB*DIM;                             // [NB*IMGL]
  float* bcat = maskb + NB*IMGL;                           // [3*DIM]

  dim3 blk(256);
  // small prep (independent of weights)
  k_cat3<<<dim3(36), blk, 0, stream>>>(bq, bk, bv, bcat);
  k_ada<<<dim3(144), blk, 0, stream>>>(temb, w_ada, b_ada, e);
  k_tmean<<<dim3(12,2), blk, 0, stream>>>(hid, tm);
  k_cond<<<dim3(48), blk, 0, stream>>>(temb, tm, w_cond, b_cond, cond);
  k_sel<<<dim3(512), blk, 0, stream>>>(hid, cond, w_sel, b_sel, maskb);
  k_lnmod<<<dim3(NTOK), blk, 0, stream>>>(hid, e, xb);
  // --- stage 1: QKV ---
  k_transpose_cvt<<<dim3(48,48),  blk, 0, stream>>>(wq,  wT,                     DIM, DIM);
  k_transpose_cvt<<<dim3(48,48),  blk, 0, stream>>>(wk,  wT + (size_t)DIM*DIM,   DIM, DIM);
  k_transpose_cvt<<<dim3(48,48),  blk, 0, stream>>>(wvw, wT + (size_t)2*DIM*DIM, DIM, DIM);
  k_gemm<0><<<dim3(24,20,3), blk, 0, stream>>>(xb, wT, bcat, qkvF, (u16*)nullptr,
      DIM, DIM, DIM, 0, (size_t)DIM*DIM, (size_t)NTOK*DIM, (size_t)DIM,
      nullptr, nullptr, nullptr);
  k_qkpost<<<dim3(NTOK,2), blk, 0, stream>>>(qkvF, rcos, rsin, qs, ksc, qb, kbb);
  k_vpost<<<dim3(48,20,2), blk, 0, stream>>>(qkvF, vtb);
  // qkvF dead; storage becomes `cat`. attention -> cat[:, 0:3072]
  k_attn<<<dim3(20,48), blk, 0, stream>>>(qb, kbb, vtb, cat);
  // --- stage 2: MLP1 (gelu) -> cat[:, 3072:] ---
  k_transpose_cvt<<<dim3(192,48), blk, 0, stream>>>(w1, wT, DIM, MLPD);
  k_gemm<1><<<dim3(96,20), blk, 0, stream>>>(xb, wT, b1, (float*)nullptr, cat,
      DIM, DIM, CATK, DIM, 0, 0, 0, nullptr, nullptr, nullptr);
  // --- stage 3: W2 split-K=4 -> accum, then fused epilogue -> out ---
  k_transpose_cvt<<<dim3(48,240), blk, 0, stream>>>(w2, wT, CATK, DIM);
  k_zero<<<dim3(NTOK*DIM/4/256), blk, 0, stream>>>(accum, NTOK*DIM/4);
  k_gemm<3><<<dim3(24,20,WSPLIT), blk, 0, stream>>>(cat, wT, b2, accum, (u16*)nullptr,
      CATK, CATK/WSPLIT, DIM, 0, 0, 0, 0, nullptr, nullptr, nullptr);
  k_w2epi<<<dim3(NTOK), blk, 0, stream>>>(accum, b2, hid, e, maskb, outp);
}